// Round 3
// baseline (2912.202 us; speedup 1.0000x reference)
//
#include <hip/hip_runtime.h>
#include <hip/hip_bf16.h>

// KmeansQuantizer: nearest centroid. feat [65536][768] f32, clusters [1024][768] f32
// -> out [65536] int32.  argmin ||x-c||^2 == argmin (c2 - 2 x.c).
//
// Strategy: bf16 MFMA approximate pass with certified-margin classification,
// then exact fp32 repair of the ~7% uncertain rows.
//  - unflagged: runner-up gap >= MARGIN -> approx argmin is provably exact
//  - LIGHT: only top-2 within margin -> rescore {i1,i2} exactly
//  - HEAVY: >=3 candidates within margin -> full fp32 rescan of the row

#define D_DIM 768
#define MARGIN 2.0f
#define LIGHTF (1 << 20)
#define HEAVYF (1 << 21)

typedef short bf16x8 __attribute__((ext_vector_type(8)));
typedef float f32x4  __attribute__((ext_vector_type(4)));

// ---------------- c2 kernel (round-1, proven) ----------------
__global__ __launch_bounds__(256) void c2_kernel(const float* __restrict__ clusters,
                                                 float* __restrict__ c2) {
    const int wave = threadIdx.x >> 6;
    const int lane = threadIdx.x & 63;
    const int c = blockIdx.x * 4 + wave;
    const float4* row = (const float4*)(clusters + (size_t)c * D_DIM);
    float s = 0.0f;
    #pragma unroll
    for (int k4 = 0; k4 < D_DIM / 4 / 64; ++k4) {
        float4 v = row[k4 * 64 + lane];
        s += v.x * v.x + v.y * v.y + v.z * v.z + v.w * v.w;
    }
    #pragma unroll
    for (int off = 32; off > 0; off >>= 1) s += __shfl_down(s, off, 64);
    if (lane == 0) c2[c] = s;
}

// ---------------- approx pass helpers ----------------
struct Stage { float4 a0, a1; };

__device__ inline Stage ldst(const float* p) {
    Stage s;
    s.a0 = *(const float4*)p;
    s.a1 = *(const float4*)(p + 4);
    return s;
}

__device__ inline void wrst(short* dst, const Stage& s) {
    union { __hip_bfloat162 h2[4]; bf16x8 v8; } u;
    u.h2[0] = __float22bfloat162_rn(float2{s.a0.x, s.a0.y});
    u.h2[1] = __float22bfloat162_rn(float2{s.a0.z, s.a0.w});
    u.h2[2] = __float22bfloat162_rn(float2{s.a1.x, s.a1.y});
    u.h2[3] = __float22bfloat162_rn(float2{s.a1.z, s.a1.w});
    *(bf16x8*)dst = u.v8;
}

// merge two sorted (v1,v2,v3) triples keeping indices of first two
__device__ inline void merge3(float& v1, int& i1, float& v2, int& i2, float& v3,
                              float ov1, int oi1, float ov2, int oi2, float ov3) {
    float m1, m2, m3; int j1, j2;
    if (ov1 < v1) {
        m1 = ov1; j1 = oi1;
        if (v1 <= ov2) { m2 = v1;  j2 = i1;  m3 = fminf(ov2, v2); }
        else           { m2 = ov2; j2 = oi2; m3 = fminf(ov3, v1); }
    } else {
        m1 = v1; j1 = i1;
        if (ov1 <= v2) { m2 = ov1; j2 = oi1; m3 = fminf(v2, ov2); }
        else           { m2 = v2;  j2 = i2;  m3 = fminf(v3, ov1); }
    }
    v1 = m1; i1 = j1; v2 = m2; i2 = j2; v3 = m3;
}

// ---------------- pass 1: bf16 MFMA + top-3 tracking ----------------
// block: 128 rows x (ct-loop over 8 col-tiles of 128). 4 waves in 2x2, each 64x64.
__global__ __launch_bounds__(256, 2) void approx_kernel(const float* __restrict__ feat,
                                                        const float* __restrict__ clusters,
                                                        const float* __restrict__ c2v,
                                                        int* __restrict__ out) {
    __shared__ short As[4096];     // 8 frags x 64 lanes x 8 bf16, fragment-linear
    __shared__ short Bs[4096];
    __shared__ float redv[1280];   // [128 rows][2 wc][v1,i1,v2,i2,v3]

    const int t    = threadIdx.x;
    const int lane = t & 63;
    const int wid  = t >> 6;
    const int wr   = wid >> 1, wc = wid & 1;
    const int row0 = blockIdx.x * 128;

    // staging: thread t fills fragment-lane slots t and t+256
    const int sl   = t & 63;
    const int sfi  = t >> 6;                 // 0..3 (slot0), +4 (slot1)
    const int srow = sl & 15;
    const int skof = (sl >> 4) * 8;

    const float* aBase0 = feat + (size_t)(row0 + sfi * 16 + srow) * D_DIM + skof;
    const float* aBase1 = feat + (size_t)(row0 + (sfi + 4) * 16 + srow) * D_DIM + skof;

    float v1[16], v2[16], v3[16]; int i1[16], i2[16];
    #pragma unroll
    for (int s = 0; s < 16; ++s) { v1[s] = v2[s] = v3[s] = 3.4e38f; i1[s] = i2[s] = 0; }

    const float* aptr0 = aBase0;
    const float* aptr1 = aBase1;

    for (int ct = 0; ct < 8; ++ct) {
        const float* bptr0 = clusters + (size_t)(ct * 128 + sfi * 16 + srow) * D_DIM + skof;
        const float* bptr1 = clusters + (size_t)(ct * 128 + (sfi + 4) * 16 + srow) * D_DIM + skof;

        f32x4 acc[4][4];
        #pragma unroll
        for (int i = 0; i < 4; ++i)
            #pragma unroll
            for (int j = 0; j < 4; ++j) acc[i][j] = f32x4{0.f, 0.f, 0.f, 0.f};

        // prologue prefetch (k0 = 0)
        Stage sA0 = ldst(aptr0), sA1 = ldst(aptr1);
        Stage sB0 = ldst(bptr0), sB1 = ldst(bptr1);

        for (int k0 = 0; k0 < D_DIM; k0 += 32) {
            __syncthreads();                       // previous tile reads done
            wrst(As + t * 8, sA0);  wrst(As + t * 8 + 2048, sA1);
            wrst(Bs + t * 8, sB0);  wrst(Bs + t * 8 + 2048, sB1);
            __syncthreads();
            if (k0 + 32 < D_DIM) {                 // issue next loads early (T14)
                aptr0 += 32; aptr1 += 32; bptr0 += 32; bptr1 += 32;
                sA0 = ldst(aptr0); sA1 = ldst(aptr1);
                sB0 = ldst(bptr0); sB1 = ldst(bptr1);
            }
            bf16x8 a[4], b[4];
            #pragma unroll
            for (int i = 0; i < 4; ++i) a[i] = *(const bf16x8*)&As[((wr * 4 + i) * 64 + lane) * 8];
            #pragma unroll
            for (int j = 0; j < 4; ++j) b[j] = *(const bf16x8*)&Bs[((wc * 4 + j) * 64 + lane) * 8];
            #pragma unroll
            for (int i = 0; i < 4; ++i)
                #pragma unroll
                for (int j = 0; j < 4; ++j)
                    acc[i][j] = __builtin_amdgcn_mfma_f32_16x16x32_bf16(a[i], b[j], acc[i][j], 0, 0, 0);
        }
        aptr0 -= 736; aptr1 -= 736;                // rewind 23 steps for next ct

        // epilogue: score = c2 - 2*dot, top-3 update.
        // C/D layout: col = lane&15, row = (lane>>4)*4 + reg   [m89]
        #pragma unroll
        for (int j = 0; j < 4; ++j) {
            const int col = ct * 128 + wc * 64 + j * 16 + (lane & 15);
            const float cc = c2v[col];
            #pragma unroll
            for (int i = 0; i < 4; ++i)
                #pragma unroll
                for (int r = 0; r < 4; ++r) {
                    const float sc = fmaf(-2.0f, acc[i][j][r], cc);
                    const int s = i * 4 + r;
                    if (sc < v1[s])      { v3[s]=v2[s]; v2[s]=v1[s]; i2[s]=i1[s]; v1[s]=sc; i1[s]=col; }
                    else if (sc < v2[s]) { v3[s]=v2[s]; v2[s]=sc; i2[s]=col; }
                    else if (sc < v3[s]) { v3[s]=sc; }
                }
        }
    }

    // reduce across the 16 lanes sharing (lane>>4) -- they hold the same rows
    #pragma unroll
    for (int m = 1; m < 16; m <<= 1) {
        #pragma unroll
        for (int s = 0; s < 16; ++s) {
            float ov1 = __shfl_xor(v1[s], m, 64);
            int   oi1 = __shfl_xor(i1[s], m, 64);
            float ov2 = __shfl_xor(v2[s], m, 64);
            int   oi2 = __shfl_xor(i2[s], m, 64);
            float ov3 = __shfl_xor(v3[s], m, 64);
            merge3(v1[s], i1[s], v2[s], i2[s], v3[s], ov1, oi1, ov2, oi2, ov3);
        }
    }

    if ((lane & 15) == 0) {
        const int g = lane >> 4;
        #pragma unroll
        for (int i = 0; i < 4; ++i)
            #pragma unroll
            for (int r = 0; r < 4; ++r) {
                const int rowl = wr * 64 + i * 16 + g * 4 + r;
                float* e = &redv[(rowl * 2 + wc) * 5];
                const int s = i * 4 + r;
                e[0] = v1[s]; e[1] = __int_as_float(i1[s]);
                e[2] = v2[s]; e[3] = __int_as_float(i2[s]); e[4] = v3[s];
            }
    }
    __syncthreads();

    if (t < 128) {
        const float* e0 = &redv[(t * 2 + 0) * 5];
        const float* e1 = &redv[(t * 2 + 1) * 5];
        float fv1 = e0[0]; int fi1 = __float_as_int(e0[1]);
        float fv2 = e0[2]; int fi2 = __float_as_int(e0[3]); float fv3 = e0[4];
        merge3(fv1, fi1, fv2, fi2, fv3,
               e1[0], __float_as_int(e1[1]), e1[2], __float_as_int(e1[3]), e1[4]);
        int res;
        if (fv2 - fv1 >= MARGIN)      res = fi1;                          // certified
        else if (fv3 - fv1 >= MARGIN) res = fi1 | (fi2 << 10) | LIGHTF;   // top-2 candidates
        else                          res = fi1 | HEAVYF;                 // full rescan
        out[row0 + t] = res;
    }
}

// ---------------- pass 2a: LIGHT rows -- exact fp32 rescore of {i1,i2} ----------------
__global__ __launch_bounds__(256) void light_kernel(const float* __restrict__ feat,
                                                    const float* __restrict__ clusters,
                                                    const float* __restrict__ c2v,
                                                    int* __restrict__ out) {
    const int wid  = threadIdx.x >> 6;
    const int lane = threadIdx.x & 63;
    const int rbase = (blockIdx.x * 4 + wid) * 16;
    for (int rr = 0; rr < 16; ++rr) {
        const int row = rbase + rr;
        const int enc = out[row];
        if (!(enc & LIGHTF)) continue;
        const int ia = enc & 1023, ib = (enc >> 10) & 1023;
        const float* fr = feat + (size_t)row * D_DIM + lane * 12;
        const float4 x0 = *(const float4*)fr;
        const float4 x1 = *(const float4*)(fr + 4);
        const float4 x2 = *(const float4*)(fr + 8);
        float d[2];
        const int cs[2] = {ia, ib};
        #pragma unroll
        for (int q = 0; q < 2; ++q) {
            const float* cr = clusters + (size_t)cs[q] * D_DIM + lane * 12;
            const float4 y0 = *(const float4*)cr;
            const float4 y1 = *(const float4*)(cr + 4);
            const float4 y2 = *(const float4*)(cr + 8);
            float p = x0.x * y0.x;
            p = fmaf(x0.y, y0.y, p); p = fmaf(x0.z, y0.z, p); p = fmaf(x0.w, y0.w, p);
            p = fmaf(x1.x, y1.x, p); p = fmaf(x1.y, y1.y, p); p = fmaf(x1.z, y1.z, p);
            p = fmaf(x1.w, y1.w, p); p = fmaf(x2.x, y2.x, p); p = fmaf(x2.y, y2.y, p);
            p = fmaf(x2.z, y2.z, p); p = fmaf(x2.w, y2.w, p);
            #pragma unroll
            for (int m = 1; m < 64; m <<= 1) p += __shfl_xor(p, m, 64);
            d[q] = p;
        }
        const float sa = c2v[ia] - 2.0f * d[0];
        const float sb = c2v[ib] - 2.0f * d[1];
        const int res = (sb < sa || (sb == sa && ib < ia)) ? ib : ia;
        if (lane == 0) out[row] = res;
    }
}

// ---------------- pass 2b: HEAVY rows -- full fp32 rescan ----------------
__global__ __launch_bounds__(256) void heavy_kernel(const float* __restrict__ feat,
                                                    const float* __restrict__ clusters,
                                                    const float* __restrict__ c2v,
                                                    int* __restrict__ out) {
    __shared__ float frow[768];
    __shared__ float rv[256];
    __shared__ int   ridx[256];
    const int t = threadIdx.x;
    for (int rr = 0; rr < 8; ++rr) {
        const int row = blockIdx.x * 8 + rr;
        const int enc = out[row];          // uniform across block
        if (!(enc & HEAVYF)) continue;
        for (int i = t; i < 192; i += 256)
            *(float4*)&frow[i * 4] = *(const float4*)(feat + (size_t)row * D_DIM + i * 4);
        __syncthreads();
        float bv = 3.4e38f; int bi = 0;
        for (int c = t; c < 1024; c += 256) {
            const float* cr = clusters + (size_t)c * D_DIM;
            float dsum = 0.0f;
            #pragma unroll 4
            for (int k = 0; k < 768; k += 4) {
                const float4 y = *(const float4*)(cr + k);
                dsum = fmaf(frow[k],     y.x, dsum);
                dsum = fmaf(frow[k + 1], y.y, dsum);
                dsum = fmaf(frow[k + 2], y.z, dsum);
                dsum = fmaf(frow[k + 3], y.w, dsum);
            }
            const float sc = c2v[c] - 2.0f * dsum;
            if (sc < bv) { bv = sc; bi = c; }      // ascending c -> first-min
        }
        rv[t] = bv; ridx[t] = bi;
        __syncthreads();
        for (int s = 128; s > 0; s >>= 1) {
            if (t < s) {
                const float v = rv[t + s]; const int ix = ridx[t + s];
                if (v < rv[t] || (v == rv[t] && ix < ridx[t])) { rv[t] = v; ridx[t] = ix; }
            }
            __syncthreads();
        }
        if (t == 0) out[row] = ridx[0];
        __syncthreads();
    }
}

extern "C" void kernel_launch(void* const* d_in, const int* in_sizes, int n_in,
                              void* d_out, int out_size, void* d_ws, size_t ws_size,
                              hipStream_t stream) {
    const float* feat     = (const float*)d_in[0];
    const float* clusters = (const float*)d_in[1];
    int*   out = (int*)d_out;
    float* c2  = (float*)d_ws;                     // 4 KB scratch

    const int M = in_sizes[0] / D_DIM;             // 65536
    const int C = in_sizes[1] / D_DIM;             // 1024

    c2_kernel<<<C / 4, 256, 0, stream>>>(clusters, c2);
    approx_kernel<<<M / 128, 256, 0, stream>>>(feat, clusters, c2, out);
    light_kernel<<<M / 64, 256, 0, stream>>>(feat, clusters, c2, out);
    heavy_kernel<<<M / 8, 256, 0, stream>>>(feat, clusters, c2, out);
}

// Round 4
// 1505.879 us; speedup vs baseline: 1.9339x; 1.9339x over previous
//
#include <hip/hip_runtime.h>
#include <hip/hip_bf16.h>

// KmeansQuantizer: nearest centroid. feat [65536][768] f32, clusters [1024][768] f32
// -> out [65536] int32.  argmin ||x-c||^2 == argmin (c2 - 2 x.c).
//
// bf16 MFMA approximate pass (A persistent in LDS, packed-u32 top-3, certified
// margin) + exact fp32 repair of uncertain rows (LIGHT: top-2 rescore, HEAVY:
// full rescan).  Round-3 post-mortem: 80-reg top-3 state + 64-reg acc spilled
// (3.6 GB scratch writes).  This version: ~90 live regs/thread, no spill.

#define D_DIM 768
#define NKF   24              // 768 / 32
#define QMARGIN 2.5f          // quantized-gap cert: 2.5 - 0.5 quant = 2.0 bf16 margin (proven r3)
#define LIGHTF (1 << 20)
#define HEAVYF (1 << 21)

typedef short bf16x8 __attribute__((ext_vector_type(8)));
typedef float f32x4  __attribute__((ext_vector_type(4)));

__device__ inline unsigned umin_(unsigned a, unsigned b) { return a < b ? a : b; }
__device__ inline unsigned umax_(unsigned a, unsigned b) { return a > b ? a : b; }

// ---------------- c2 kernel (proven r1/r3) ----------------
__global__ __launch_bounds__(256) void c2_kernel(const float* __restrict__ clusters,
                                                 float* __restrict__ c2) {
    const int wave = threadIdx.x >> 6;
    const int lane = threadIdx.x & 63;
    const int c = blockIdx.x * 4 + wave;
    const float4* row = (const float4*)(clusters + (size_t)c * D_DIM);
    float s = 0.0f;
    #pragma unroll
    for (int k4 = 0; k4 < D_DIM / 4 / 64; ++k4) {
        float4 v = row[k4 * 64 + lane];
        s += v.x * v.x + v.y * v.y + v.z * v.z + v.w * v.w;
    }
    #pragma unroll
    for (int off = 32; off > 0; off >>= 1) s += __shfl_down(s, off, 64);
    if (lane == 0) c2[c] = s;
}

__device__ inline void wrB(short* dst, float4 a, float4 b) {
    union { __hip_bfloat162 h2[4]; bf16x8 v; } u;
    u.h2[0] = __float22bfloat162_rn(float2{a.x, a.y});
    u.h2[1] = __float22bfloat162_rn(float2{a.z, a.w});
    u.h2[2] = __float22bfloat162_rn(float2{b.x, b.y});
    u.h2[3] = __float22bfloat162_rn(float2{b.z, b.w});
    *(bf16x8*)dst = u.v;
}

// ---------------- pass 1: bf16 MFMA, A-persistent-LDS, packed top-3 ----------------
// block = 32 rows; 4 waves each own a 32-col band of the 128-col ct tile.
__global__ __launch_bounds__(256, 2) void approx_kernel(const float* __restrict__ feat,
                                                        const float* __restrict__ clusters,
                                                        const float* __restrict__ c2v,
                                                        int* __restrict__ out) {
    __shared__ short As[24576];      // 48 slots (kf*2+i) x 64 lanes x 8 bf16 = 48 KB, persistent
    __shared__ short Bs[2][4096];    // double buffer: 8 slots x 64 x 8 bf16 = 8 KB each

    const int t    = threadIdx.x;
    const int lane = t & 63;
    const int w    = t >> 6;
    const int ll   = lane & 15;
    const int lh   = lane >> 4;
    const int row0 = blockIdx.x * 32;

    // ---- Phase 0: stage A (32x768 f32 -> bf16 fragment-linear LDS), once ----
    {
        const float4* src = (const float4*)(feat + (size_t)row0 * D_DIM);
        #pragma unroll
        for (int it = 0; it < 24; ++it) {
            const int idx = it * 256 + t;            // 0..6143, coalesced float4
            const int r   = idx / 192;               // row 0..31
            const int k   = (idx - r * 192) * 4;     // k 0..764
            const float4 v = src[idx];
            const int slot = (k >> 5) * 2 + (r >> 4);
            const int ln   = ((k >> 3) & 3) * 16 + (r & 15);
            const int el   = k & 7;                  // 0 or 4
            union { __hip_bfloat162 h2[2]; uint2 u; } cv;
            cv.h2[0] = __float22bfloat162_rn(float2{v.x, v.y});
            cv.h2[1] = __float22bfloat162_rn(float2{v.z, v.w});
            *(uint2*)&As[(slot * 64 + ln) * 8 + el] = cv.u;
        }
    }

    unsigned t1[8], t2[8], t3[8];
    #pragma unroll
    for (int s = 0; s < 8; ++s) { t1[s] = t2[s] = t3[s] = 0xFFFFFFFFu; }

    int cur = 0;
    for (int ct = 0; ct < 8; ++ct) {
        // per-thread B staging: slots 2w, 2w+1 at lane position `lane`
        const float* pB0 = clusters + (size_t)(ct * 128 + (2 * w) * 16 + ll) * D_DIM + lh * 8;
        const float* pB1 = clusters + (size_t)(ct * 128 + (2 * w + 1) * 16 + ll) * D_DIM + lh * 8;
        float4 s0a = *(const float4*)pB0, s0b = *(const float4*)(pB0 + 4);
        float4 s1a = *(const float4*)pB1, s1b = *(const float4*)(pB1 + 4);

        __syncthreads();                 // drain prev-ct reads (also publishes As on ct=0)
        wrB(&Bs[cur][((2 * w) * 64 + lane) * 8], s0a, s0b);
        wrB(&Bs[cur][((2 * w + 1) * 64 + lane) * 8], s1a, s1b);
        __syncthreads();

        f32x4 acc[2][2];
        #pragma unroll
        for (int i = 0; i < 2; ++i)
            #pragma unroll
            for (int j = 0; j < 2; ++j) acc[i][j] = f32x4{0.f, 0.f, 0.f, 0.f};

        for (int kf = 0; kf < NKF; ++kf) {
            if (kf + 1 < NKF) {          // issue next-step loads early (T14)
                pB0 += 32; pB1 += 32;
                s0a = *(const float4*)pB0; s0b = *(const float4*)(pB0 + 4);
                s1a = *(const float4*)pB1; s1b = *(const float4*)(pB1 + 4);
            }
            bf16x8 a0 = *(const bf16x8*)&As[((kf * 2 + 0) * 64 + lane) * 8];
            bf16x8 a1 = *(const bf16x8*)&As[((kf * 2 + 1) * 64 + lane) * 8];
            bf16x8 b0 = *(const bf16x8*)&Bs[cur][((2 * w + 0) * 64 + lane) * 8];
            bf16x8 b1 = *(const bf16x8*)&Bs[cur][((2 * w + 1) * 64 + lane) * 8];
            acc[0][0] = __builtin_amdgcn_mfma_f32_16x16x32_bf16(a0, b0, acc[0][0], 0, 0, 0);
            acc[0][1] = __builtin_amdgcn_mfma_f32_16x16x32_bf16(a0, b1, acc[0][1], 0, 0, 0);
            acc[1][0] = __builtin_amdgcn_mfma_f32_16x16x32_bf16(a1, b0, acc[1][0], 0, 0, 0);
            acc[1][1] = __builtin_amdgcn_mfma_f32_16x16x32_bf16(a1, b1, acc[1][1], 0, 0, 0);
            if (kf + 1 < NKF) {
                wrB(&Bs[cur ^ 1][((2 * w) * 64 + lane) * 8], s0a, s0b);
                wrB(&Bs[cur ^ 1][((2 * w + 1) * 64 + lane) * 8], s1a, s1b);
                __syncthreads();
                cur ^= 1;
            }
        }

        // epilogue: pack scores (positive after +4096 bias -> bits monotone) and
        // sort-insert into per-row top-3.  quantum <= 0.5 for |s| < 4096.
        #pragma unroll
        for (int j = 0; j < 2; ++j) {
            const int col = ct * 128 + w * 32 + j * 16 + ll;
            const float cc = c2v[col] + 4096.0f;
            #pragma unroll
            for (int i = 0; i < 2; ++i)
                #pragma unroll
                for (int r = 0; r < 4; ++r) {
                    const float sc = fmaf(-2.0f, acc[i][j][r], cc);
                    const unsigned u = (__float_as_uint(sc) & 0xFFFFFC00u) | (unsigned)col;
                    const int s = i * 4 + r;
                    const unsigned x = umin_(u, t1[s]);
                    const unsigned y = umax_(u, t1[s]);
                    t1[s] = x;
                    const unsigned z = umin_(y, t2[s]);
                    const unsigned q = umax_(y, t2[s]);
                    t2[s] = z;
                    t3[s] = umin_(q, t3[s]);
                }
        }
    }

    // merge sorted triples across the 16 col-lanes (same rows)
    #pragma unroll
    for (int m = 1; m < 16; m <<= 1) {
        #pragma unroll
        for (int s = 0; s < 8; ++s) {
            const unsigned o1 = (unsigned)__shfl_xor((int)t1[s], m, 64);
            const unsigned o2 = (unsigned)__shfl_xor((int)t2[s], m, 64);
            const unsigned o3 = (unsigned)__shfl_xor((int)t3[s], m, 64);
            const unsigned r1 = umin_(t1[s], o1);
            const unsigned x  = umax_(t1[s], o1);
            const unsigned y  = umin_(t2[s], o2);
            const unsigned r2 = umin_(x, y);
            const unsigned r3 = umin_(umax_(x, y), umin_(t3[s], o3));
            t1[s] = r1; t2[s] = r2; t3[s] = r3;
        }
    }

    // cross-wave merge (4 waves share all 32 rows) via tiny LDS overlay on Bs
    __syncthreads();
    unsigned* sm = (unsigned*)&Bs[0][0];     // [32 rows][4 waves][3]
    if (ll == 0) {
        #pragma unroll
        for (int i = 0; i < 2; ++i)
            #pragma unroll
            for (int r = 0; r < 4; ++r) {
                const int row = i * 16 + lh * 4 + r;
                const int s = i * 4 + r;
                sm[(row * 4 + w) * 3 + 0] = t1[s];
                sm[(row * 4 + w) * 3 + 1] = t2[s];
                sm[(row * 4 + w) * 3 + 2] = t3[s];
            }
    }
    __syncthreads();
    if (t < 32) {
        unsigned m1 = sm[(t * 4 + 0) * 3 + 0];
        unsigned m2 = sm[(t * 4 + 0) * 3 + 1];
        unsigned m3 = sm[(t * 4 + 0) * 3 + 2];
        #pragma unroll
        for (int wv = 1; wv < 4; ++wv) {
            const unsigned o1 = sm[(t * 4 + wv) * 3 + 0];
            const unsigned o2 = sm[(t * 4 + wv) * 3 + 1];
            const unsigned o3 = sm[(t * 4 + wv) * 3 + 2];
            const unsigned r1 = umin_(m1, o1);
            const unsigned x  = umax_(m1, o1);
            const unsigned y  = umin_(m2, o2);
            const unsigned r2 = umin_(x, y);
            const unsigned r3 = umin_(umax_(x, y), umin_(m3, o3));
            m1 = r1; m2 = r2; m3 = r3;
        }
        const float v1 = __uint_as_float(m1 & 0xFFFFFC00u) - 4096.0f;
        const float v2 = __uint_as_float(m2 & 0xFFFFFC00u) - 4096.0f;
        const float v3 = __uint_as_float(m3 & 0xFFFFFC00u) - 4096.0f;
        const int i1 = m1 & 1023, i2 = m2 & 1023;
        int res;
        if (v2 - v1 >= QMARGIN)      res = i1;                          // certified exact
        else if (v3 - v1 >= QMARGIN) res = i1 | (i2 << 10) | LIGHTF;    // top-2 rescore
        else                         res = i1 | HEAVYF;                 // full rescan
        out[row0 + t] = res;
    }
}

// ---------------- pass 2a: LIGHT rows -- exact fp32 rescore of {i1,i2} (proven r3) ----------------
__global__ __launch_bounds__(256) void light_kernel(const float* __restrict__ feat,
                                                    const float* __restrict__ clusters,
                                                    const float* __restrict__ c2v,
                                                    int* __restrict__ out) {
    const int wid  = threadIdx.x >> 6;
    const int lane = threadIdx.x & 63;
    const int rbase = (blockIdx.x * 4 + wid) * 16;
    for (int rr = 0; rr < 16; ++rr) {
        const int row = rbase + rr;
        const int enc = out[row];
        if (!(enc & LIGHTF)) continue;
        const int ia = enc & 1023, ib = (enc >> 10) & 1023;
        const float* fr = feat + (size_t)row * D_DIM + lane * 12;
        const float4 x0 = *(const float4*)fr;
        const float4 x1 = *(const float4*)(fr + 4);
        const float4 x2 = *(const float4*)(fr + 8);
        float d[2];
        const int cs[2] = {ia, ib};
        #pragma unroll
        for (int q = 0; q < 2; ++q) {
            const float* cr = clusters + (size_t)cs[q] * D_DIM + lane * 12;
            const float4 y0 = *(const float4*)cr;
            const float4 y1 = *(const float4*)(cr + 4);
            const float4 y2 = *(const float4*)(cr + 8);
            float p = x0.x * y0.x;
            p = fmaf(x0.y, y0.y, p); p = fmaf(x0.z, y0.z, p); p = fmaf(x0.w, y0.w, p);
            p = fmaf(x1.x, y1.x, p); p = fmaf(x1.y, y1.y, p); p = fmaf(x1.z, y1.z, p);
            p = fmaf(x1.w, y1.w, p); p = fmaf(x2.x, y2.x, p); p = fmaf(x2.y, y2.y, p);
            p = fmaf(x2.z, y2.z, p); p = fmaf(x2.w, y2.w, p);
            #pragma unroll
            for (int m = 1; m < 64; m <<= 1) p += __shfl_xor(p, m, 64);
            d[q] = p;
        }
        const float sa = c2v[ia] - 2.0f * d[0];
        const float sb = c2v[ib] - 2.0f * d[1];
        const int res = (sb < sa || (sb == sa && ib < ia)) ? ib : ia;
        if (lane == 0) out[row] = res;
    }
}

// ---------------- pass 2b: HEAVY rows -- full fp32 rescan (proven r3) ----------------
__global__ __launch_bounds__(256) void heavy_kernel(const float* __restrict__ feat,
                                                    const float* __restrict__ clusters,
                                                    const float* __restrict__ c2v,
                                                    int* __restrict__ out) {
    __shared__ float frow[768];
    __shared__ float rv[256];
    __shared__ int   ridx[256];
    const int t = threadIdx.x;
    for (int rr = 0; rr < 8; ++rr) {
        const int row = blockIdx.x * 8 + rr;
        const int enc = out[row];          // uniform across block
        if (!(enc & HEAVYF)) continue;
        for (int i = t; i < 192; i += 256)
            *(float4*)&frow[i * 4] = *(const float4*)(feat + (size_t)row * D_DIM + i * 4);
        __syncthreads();
        float bv = 3.4e38f; int bi = 0;
        for (int c = t; c < 1024; c += 256) {
            const float* cr = clusters + (size_t)c * D_DIM;
            float dsum = 0.0f;
            #pragma unroll 4
            for (int k = 0; k < 768; k += 4) {
                const float4 y = *(const float4*)(cr + k);
                dsum = fmaf(frow[k],     y.x, dsum);
                dsum = fmaf(frow[k + 1], y.y, dsum);
                dsum = fmaf(frow[k + 2], y.z, dsum);
                dsum = fmaf(frow[k + 3], y.w, dsum);
            }
            const float sc = c2v[c] - 2.0f * dsum;
            if (sc < bv) { bv = sc; bi = c; }      // ascending c -> first-min
        }
        rv[t] = bv; ridx[t] = bi;
        __syncthreads();
        for (int s = 128; s > 0; s >>= 1) {
            if (t < s) {
                const float v = rv[t + s]; const int ix = ridx[t + s];
                if (v < rv[t] || (v == rv[t] && ix < ridx[t])) { rv[t] = v; ridx[t] = ix; }
            }
            __syncthreads();
        }
        if (t == 0) out[row] = ridx[0];
        __syncthreads();
    }
}

extern "C" void kernel_launch(void* const* d_in, const int* in_sizes, int n_in,
                              void* d_out, int out_size, void* d_ws, size_t ws_size,
                              hipStream_t stream) {
    const float* feat     = (const float*)d_in[0];
    const float* clusters = (const float*)d_in[1];
    int*   out = (int*)d_out;
    float* c2  = (float*)d_ws;                     // 4 KB scratch

    const int M = in_sizes[0] / D_DIM;             // 65536
    const int C = in_sizes[1] / D_DIM;             // 1024

    c2_kernel<<<C / 4, 256, 0, stream>>>(clusters, c2);
    approx_kernel<<<M / 32, 256, 0, stream>>>(feat, clusters, c2, out);
    light_kernel<<<M / 64, 256, 0, stream>>>(feat, clusters, c2, out);
    heavy_kernel<<<M / 8, 256, 0, stream>>>(feat, clusters, c2, out);
}